// Round 1
// baseline (85.014 us; speedup 1.0000x reference)
//
#include <hip/hip_runtime.h>
#include <hip/hip_bf16.h>

// LatencyEncoder: out[b,f,t] = (t == round(99*(1-sigmoid(x+0.01*noise)))) && sigmoid > 0.5
// B*F = 1,048,576 pairs, T = 100. Output 419.4 MB f32 -> write-BW bound.
//
// Block of 256 threads owns 256 consecutive (b,f) pairs:
//   Phase 1: each thread computes its pair's spike latency (-1 if no spike) -> LDS.
//   Phase 2: block writes its contiguous 256*100-float region as 6400 float4s,
//            thread t stores float4 index t + k*256 (perfectly coalesced, 1 KB/wave/instr).
// Latency math in f64 to match the harness's numpy reference rounding decisions
// (a single bucket flip => absmax 1.0 fail; f64 agreement band ~1e-14).

#define TIME_STEPS 100
#define PAIRS_PER_BLOCK 256
#define F4_PER_PAIR (TIME_STEPS / 4)                 // 25
#define F4_PER_BLOCK (PAIRS_PER_BLOCK * F4_PER_PAIR) // 6400
#define F4_PER_THREAD (F4_PER_BLOCK / 256)           // 25

__global__ __launch_bounds__(256) void latency_encode_kernel(
    const float* __restrict__ x, const float* __restrict__ noise,
    float* __restrict__ out, int npairs) {
  __shared__ int lat_s[PAIRS_PER_BLOCK];

  const int tid = threadIdx.x;
  const int pairBase = blockIdx.x * PAIRS_PER_BLOCK;
  const int p = pairBase + tid;

  // ---- Phase 1: per-pair latency in f64 (match numpy f64 reference) ----
  int lat = -1;
  if (p < npairs) {
    double xn = (double)x[p] + (double)noise[p] * 0.01;
    double s = 1.0 / (1.0 + exp(-xn));
    double l = (1.0 - s) * 99.0;
    int li = (int)rint(l);
    li = li < 0 ? 0 : (li > 99 ? 99 : li);
    lat = (s > 0.5) ? li : -1;  // -1: no spike, row stays all-zero
  }
  lat_s[tid] = lat;
  __syncthreads();

  // ---- Phase 2: coalesced float4 writes of the block's output region ----
  float4* o4 = (float4*)(out + (size_t)pairBase * TIME_STEPS);
#pragma unroll
  for (int k = 0; k < F4_PER_THREAD; ++k) {
    const int fi4 = tid + k * 256;        // 0..6399, consecutive across lanes
    const int pl = fi4 / F4_PER_PAIR;     // pair-local index 0..255
    const int pos = (fi4 % F4_PER_PAIR) * 4;  // element offset within pair
    const int L = lat_s[pl];
    float4 v;
    v.x = (L == pos + 0) ? 1.0f : 0.0f;
    v.y = (L == pos + 1) ? 1.0f : 0.0f;
    v.z = (L == pos + 2) ? 1.0f : 0.0f;
    v.w = (L == pos + 3) ? 1.0f : 0.0f;
    if (pairBase + pl < npairs) o4[fi4] = v;
  }
}

extern "C" void kernel_launch(void* const* d_in, const int* in_sizes, int n_in,
                              void* d_out, int out_size, void* d_ws, size_t ws_size,
                              hipStream_t stream) {
  const float* x = (const float*)d_in[0];
  const float* noise = (const float*)d_in[1];
  float* out = (float*)d_out;
  const int npairs = in_sizes[0];  // 256*4096
  const int grid = (npairs + PAIRS_PER_BLOCK - 1) / PAIRS_PER_BLOCK;
  latency_encode_kernel<<<grid, 256, 0, stream>>>(x, noise, out, npairs);
}